// Round 1
// baseline (1824.979 us; speedup 1.0000x reference)
//
#include <hip/hip_runtime.h>

#define NB   8
#define LQ   2048
#define DMD  256
#define DIN  512
#define DST  16
#define MT   (NB*LQ)   // 16384 tokens

#define BM 128
#define BN 64
#define BK 16

__device__ __forceinline__ float fsilu(float x){ return x / (1.f + __expf(-x)); }

// ---------------- h = x ----------------
__global__ void k_copy(const float4* __restrict__ src, float4* __restrict__ dst, int n4){
    int i = blockIdx.x*256 + threadIdx.x;
    if(i < n4) dst[i] = src[i];
}

// ---------------- layernorm over DMD=256, one token per 64-lane wave ----------------
__global__ __launch_bounds__(256) void k_ln(const float* __restrict__ h,
                                            const float* __restrict__ g,
                                            const float* __restrict__ b,
                                            float* __restrict__ out){
    int wave = threadIdx.x >> 6, lane = threadIdx.x & 63;
    int m = blockIdx.x*4 + wave;
    const float* row = h + (size_t)m*DMD;
    float4 v = *(const float4*)(row + lane*4);
    float s  = v.x+v.y+v.z+v.w;
    float sq = v.x*v.x+v.y*v.y+v.z*v.z+v.w*v.w;
    #pragma unroll
    for(int o=32;o;o>>=1){ s += __shfl_xor(s,o,64); sq += __shfl_xor(sq,o,64); }
    float mu  = s*(1.f/DMD);
    float var = sq*(1.f/DMD) - mu*mu;
    float rs  = rsqrtf(var + 1e-5f);
    float4 gg = *(const float4*)(g + lane*4);
    float4 bb = *(const float4*)(b + lane*4);
    float4 o4;
    o4.x=(v.x-mu)*rs*gg.x+bb.x; o4.y=(v.y-mu)*rs*gg.y+bb.y;
    o4.z=(v.z-mu)*rs*gg.z+bb.z; o4.w=(v.w-mu)*rs*gg.w+bb.w;
    *(float4*)(out + (size_t)m*DMD + lane*4) = o4;
}

// ---------------- tiled f32 GEMM: C[m,n] = sum_k A[m,k]*Bw[n,k] (+C if accum) ----------------
// atrans=0: A row-major [M,K] (lda=K). atrans=1: A is AT[b][k][l], m=b*LQ+l, batch stride K*LQ.
__global__ __launch_bounds__(256,2) void k_gemm(const float* __restrict__ A,
                                                const float* __restrict__ Bw,
                                                float* __restrict__ C,
                                                int N, int K, int ldc, int atrans, int accum){
    __shared__ float As[BK][BM+4];
    __shared__ float Bs[BK][BN+4];
    const int t  = threadIdx.x;
    const int m0 = blockIdx.x * BM;
    const int n0 = blockIdx.y * BN;
    const int tx = t & 15, ty = t >> 4;
    float acc[8][4];
    #pragma unroll
    for(int i=0;i<8;i++)
        #pragma unroll
        for(int j=0;j<4;j++) acc[i][j]=0.f;

    const float* Abase; int l0 = 0;
    if(atrans){ int bb = m0 / LQ; l0 = m0 % LQ; Abase = A + (size_t)bb*K*LQ; }
    else      { Abase = A + (size_t)m0*K; }

    for(int k0=0; k0<K; k0+=BK){
        if(atrans){
            int tl = t & 127, tk = t >> 7;
            #pragma unroll
            for(int i=0;i<8;i++){
                int k = tk + i*2;
                As[k][tl] = Abase[(size_t)(k0+k)*LQ + l0 + tl];
            }
        } else {
            int tk = t & 15, tr = t >> 4;
            #pragma unroll
            for(int i=0;i<8;i++)
                As[tk][tr+i*16] = Abase[(size_t)(tr+i*16)*K + k0 + tk];
        }
        {
            int tk = t & 15, tn = t >> 4;
            #pragma unroll
            for(int i=0;i<4;i++){
                int n = tn + i*16;
                Bs[tk][n] = (n0+n < N) ? Bw[(size_t)(n0+n)*K + k0+tk] : 0.f;
            }
        }
        __syncthreads();
        #pragma unroll
        for(int k=0;k<BK;k++){
            float a[8], bv[4];
            *(float4*)&a[0] = *(const float4*)&As[k][ty*8];
            *(float4*)&a[4] = *(const float4*)&As[k][ty*8+4];
            *(float4*)&bv[0] = *(const float4*)&Bs[k][tx*4];
            #pragma unroll
            for(int i=0;i<8;i++)
                #pragma unroll
                for(int j=0;j<4;j++) acc[i][j] += a[i]*bv[j];
        }
        __syncthreads();
    }
    int n = n0 + tx*4;
    if(n < N){
        #pragma unroll
        for(int i=0;i<8;i++){
            float4* cp = (float4*)(C + (size_t)(m0+ty*8+i)*ldc + n);
            float4 v = make_float4(acc[i][0],acc[i][1],acc[i][2],acc[i][3]);
            if(accum){ float4 o = *cp; v.x+=o.x; v.y+=o.y; v.z+=o.z; v.w+=o.w; }
            *cp = v;
        }
    }
}

// ---------------- causal depthwise conv(4) + SiLU + transpose to uT[b,d,l] ----------------
__global__ __launch_bounds__(256) void k_conv(const float* __restrict__ xz,
                                              const float* __restrict__ cw,
                                              const float* __restrict__ cb,
                                              float* __restrict__ uT){
    __shared__ float us[67][65];
    int lt0 = blockIdx.x*64, d0 = blockIdx.y*64, b = blockIdx.z;
    int t = threadIdx.x;
    for(int idx=t; idx<67*64; idx+=256){
        int r = idx >> 6, c = idx & 63;
        int l = lt0 - 3 + r;
        us[r][c] = (l >= 0) ? xz[((size_t)(b*LQ + l))*1024 + d0 + c] : 0.f;
    }
    __syncthreads();
    int dl = t >> 2, lg = t & 3;
    int d = d0 + dl;
    float w0=cw[d*4+0], w1=cw[d*4+1], w2=cw[d*4+2], w3=cw[d*4+3];
    float bias = cb[d];
    float o[16];
    #pragma unroll
    for(int i=0;i<16;i++){
        int ll = lg*16 + i;
        float a = bias + w0*us[ll][dl] + w1*us[ll+1][dl] + w2*us[ll+2][dl] + w3*us[ll+3][dl];
        o[i] = fsilu(a);
    }
    float* dst = uT + ((size_t)(b*DIN + d))*LQ + lt0 + lg*16;
    #pragma unroll
    for(int i=0;i<4;i++)
        *(float4*)(dst + i*4) = make_float4(o[i*4],o[i*4+1],o[i*4+2],o[i*4+3]);
}

// ---------------- dt = softplus(dbc[:, :16] @ dtw^T + dtb), write dtT[b,d,l] ----------------
__global__ __launch_bounds__(256) void k_dt(const float* __restrict__ dbc,
                                            const float* __restrict__ w,
                                            const float* __restrict__ bias,
                                            float* __restrict__ dtT){
    int l = blockIdx.x*256 + threadIdx.x;
    int d = blockIdx.y, b = blockIdx.z;
    const float* row = dbc + (size_t)(b*LQ + l)*48;
    float4 r0 = *(const float4*)(row);
    float4 r1 = *(const float4*)(row+4);
    float4 r2 = *(const float4*)(row+8);
    float4 r3 = *(const float4*)(row+12);
    const float* wd = w + d*16;
    float acc = bias[d]
        + r0.x*wd[0] + r0.y*wd[1] + r0.z*wd[2] + r0.w*wd[3]
        + r1.x*wd[4] + r1.y*wd[5] + r1.z*wd[6] + r1.w*wd[7]
        + r2.x*wd[8] + r2.y*wd[9] + r2.z*wd[10]+ r2.w*wd[11]
        + r3.x*wd[12]+ r3.y*wd[13]+ r3.z*wd[14]+ r3.w*wd[15];
    float sp = (acc > 20.f) ? acc : log1pf(__expf(acc));
    dtT[((size_t)(b*DIN + d))*LQ + l] = sp;
}

// ---------------- transpose dbc[:,16:48] -> BT[b,s,l], CT[b,s,l] ----------------
__global__ __launch_bounds__(256) void k_bct(const float* __restrict__ dbc,
                                             float* __restrict__ BT, float* __restrict__ CT){
    int l = blockIdx.x*256 + threadIdx.x;
    int b = blockIdx.y;
    const float* row = dbc + (size_t)(b*LQ + l)*48 + 16;
    float v[32];
    #pragma unroll
    for(int j=0;j<8;j++) *(float4*)&v[j*4] = *(const float4*)(row + j*4);
    #pragma unroll
    for(int s=0;s<DST;s++){
        BT[((size_t)(b*DST+s))*LQ + l] = v[s];
        CT[((size_t)(b*DST+s))*LQ + l] = v[16+s];
    }
}

// ---------------- selective scan; yT[b,d,l] = y_scan + u*Dp ----------------
__global__ __launch_bounds__(256) void k_scan(const float* __restrict__ dtT,
                                              const float* __restrict__ uT,
                                              const float* __restrict__ BT,
                                              const float* __restrict__ CT,
                                              const float* __restrict__ A_log,
                                              const float* __restrict__ Dpv,
                                              float* __restrict__ yT){
    int b = blockIdx.y;
    int t = threadIdx.x;
    int lane = t & 63, wave = t >> 6;
    int s = lane & 15, dl = lane >> 4;
    int d = blockIdx.x*16 + wave*4 + dl;
    float Aa = -__expf(A_log[d*DST + s]);
    float dp = Dpv[d];
    const float4* dtp = (const float4*)(dtT + ((size_t)b*DIN + d)*LQ);
    const float4* up  = (const float4*)(uT  + ((size_t)b*DIN + d)*LQ);
    const float4* Bp  = (const float4*)(BT  + ((size_t)b*DST + s)*LQ);
    const float4* Cp  = (const float4*)(CT  + ((size_t)b*DST + s)*LQ);
    float4* yp = (float4*)(yT + ((size_t)b*DIN + d)*LQ);
    float hh = 0.f;
    float4 dt4 = dtp[0], u4 = up[0], B4 = Bp[0], C4 = Cp[0];
    for(int g=0; g<LQ/4; g++){
        float4 nd, nu, nB, nC;
        if(g < LQ/4 - 1){ nd = dtp[g+1]; nu = up[g+1]; nB = Bp[g+1]; nC = Cp[g+1]; }
        float dtv[4] = {dt4.x,dt4.y,dt4.z,dt4.w};
        float uv[4]  = {u4.x,u4.y,u4.z,u4.w};
        float Bv[4]  = {B4.x,B4.y,B4.z,B4.w};
        float Cv[4]  = {C4.x,C4.y,C4.z,C4.w};
        float yv[4];
        #pragma unroll
        for(int j=0;j<4;j++){
            float dA = __expf(dtv[j]*Aa);
            hh = hh*dA + dtv[j]*uv[j]*Bv[j];
            float py = hh*Cv[j];
            py += __shfl_xor(py,1,16);
            py += __shfl_xor(py,2,16);
            py += __shfl_xor(py,4,16);
            py += __shfl_xor(py,8,16);
            yv[j] = py + uv[j]*dp;
        }
        if(s==0) yp[g] = make_float4(yv[0],yv[1],yv[2],yv[3]);
        dt4=nd; u4=nu; B4=nB; C4=nC;
    }
}

// ---------------- gate: yg[m,d] = yT[b,d,l] * silu(z[m,d]) (transpose via LDS) ----------------
__global__ __launch_bounds__(256) void k_gate(const float* __restrict__ yT,
                                              const float* __restrict__ xz,
                                              float* __restrict__ yg){
    __shared__ float Tt[64][65];
    int lt0 = blockIdx.x*64, d0 = blockIdx.y*64, b = blockIdx.z;
    int t = threadIdx.x;
    int r = t >> 6, c = t & 63;
    #pragma unroll
    for(int i=0;i<16;i++){
        int d = r + i*4;
        Tt[d][c] = yT[((size_t)(b*DIN + d0 + d))*LQ + lt0 + c];
    }
    __syncthreads();
    #pragma unroll
    for(int i=0;i<16;i++){
        int l = r + i*4;
        size_t m = (size_t)b*LQ + lt0 + l;
        float z = xz[m*1024 + 512 + d0 + c];
        yg[m*DIN + d0 + c] = Tt[c][l] * fsilu(z);
    }
}

extern "C" void kernel_launch(void* const* d_in, const int* in_sizes, int n_in,
                              void* d_out, int out_size, void* d_ws, size_t ws_size,
                              hipStream_t stream){
    (void)in_sizes; (void)n_in; (void)out_size; (void)ws_size;
    const float* x        = (const float*)d_in[0];
    const float* ln_g     = (const float*)d_in[1];
    const float* ln_b     = (const float*)d_in[2];
    const float* in_w     = (const float*)d_in[3];
    const float* conv_w   = (const float*)d_in[4];
    const float* conv_b   = (const float*)d_in[5];
    const float* xproj_w  = (const float*)d_in[6];
    const float* dtproj_w = (const float*)d_in[7];
    const float* dtproj_b = (const float*)d_in[8];
    const float* A_log    = (const float*)d_in[9];
    const float* Dp       = (const float*)d_in[10];
    const float* out_w    = (const float*)d_in[11];
    float* h = (float*)d_out;
    float* ws = (float*)d_ws;

    float* xz      = ws;                          // 16,777,216 floats
    float* scratch = xz + (size_t)MT*1024;        //  4,194,304 floats (hnorm, later dbc/BT/CT)
    float* hnorm   = scratch;
    float* dbc     = scratch;
    float* BT      = scratch + 786432;
    float* CT      = BT + 262144;
    float* uT      = scratch + 4194304;           //  8,388,608
    float* dtT     = uT + 8388608;                //  8,388,608 (reused as yg)
    float* yg      = dtT;
    float* yT      = dtT + 8388608;               //  8,388,608

    k_copy<<<(MT*DMD/4 + 255)/256, 256, 0, stream>>>((const float4*)x, (float4*)h, MT*DMD/4);

    for(int li=0; li<3; li++){
        k_ln<<<MT/4, 256, 0, stream>>>(h, ln_g, ln_b, hnorm);

        dim3 g1(MT/BM, 1024/BN);
        k_gemm<<<g1, 256, 0, stream>>>(hnorm, in_w + (size_t)li*1024*DMD, xz,
                                       1024, DMD, 1024, 0, 0);

        dim3 gc(LQ/64, DIN/64, NB);
        k_conv<<<gc, 256, 0, stream>>>(xz, conv_w + (size_t)li*DIN*4, conv_b + (size_t)li*DIN, uT);

        dim3 g2(MT/BM, 1);
        k_gemm<<<g2, 256, 0, stream>>>(uT, xproj_w + (size_t)li*48*DIN, dbc,
                                       48, DIN, 48, 1, 0);

        dim3 gdt(LQ/256, DIN, NB);
        k_dt<<<gdt, 256, 0, stream>>>(dbc, dtproj_w + (size_t)li*DIN*16, dtproj_b + (size_t)li*DIN, dtT);

        dim3 gbc(LQ/256, NB);
        k_bct<<<gbc, 256, 0, stream>>>(dbc, BT, CT);

        dim3 gs(DIN/16, NB);
        k_scan<<<gs, 256, 0, stream>>>(dtT, uT, BT, CT,
                                       A_log + (size_t)li*DIN*DST, Dp + (size_t)li*DIN, yT);

        dim3 gg(LQ/64, DIN/64, NB);
        k_gate<<<gg, 256, 0, stream>>>(yT, xz, yg);

        dim3 g3(MT/BM, DMD/BN);
        k_gemm<<<g3, 256, 0, stream>>>(yg, out_w + (size_t)li*DMD*DIN, h,
                                       DMD, DIN, DMD, 0, 1);
    }
}